// Round 15
// baseline (1887.471 us; speedup 1.0000x reference)
//
#include <hip/hip_runtime.h>
#include <hip/hip_fp16.h>

#define HID  256
#define TT   2048
#define NB   128
#define NTHR 1024

typedef _Float16 hf2 __attribute__((ext_vector_type(2)));
typedef unsigned int u32x4 __attribute__((ext_vector_type(4)));

template <int CTRL>
__device__ __forceinline__ float dpp_add(float v) {
    int t = __builtin_amdgcn_update_dpp(0, __float_as_int(v), CTRL, 0xF, 0xF, true);
    return v + __int_as_float(t);
}

__device__ __forceinline__ float tanh_fast(float x) {
    float e = __expf(2.0f * x);
    float r = __builtin_amdgcn_rcpf(e + 1.0f);
    return fmaf(-2.0f, r, 1.0f);
}

__device__ __forceinline__ hf2 bc2(unsigned int u) {
    hf2 h;
    __builtin_memcpy(&h, &u, 4);
    return h;
}

// ---- prep: pack W_hh fp32 -> fp16 pairs, wave-coalesced uint4 chunks.
// u32 j = (((wv*8 + i)*64 + lane)*4 + k); thread tid=wv*64+lane owns
// rows 4*(tid>>4)+(i>>1), cols 16*(tid&15)+8*(i&1)+2k (+0 lo, +1 hi).
__global__ void pack_w(const float* __restrict__ W, unsigned int* __restrict__ out) {
    int j    = blockIdx.x * 256 + threadIdx.x;   // 0..32767
    int k    = j & 3;
    int lane = (j >> 2) & 63;
    int i    = (j >> 8) & 7;
    int wv   = j >> 11;
    int tid  = wv * 64 + lane;
    int row  = 4 * (tid >> 4) + (i >> 1);
    int col  = 16 * (tid & 15) + 8 * (i & 1) + 2 * k;
    _Float16 lo = (_Float16)W[row * HID + col];
    _Float16 hi = (_Float16)W[row * HID + col + 1];
    unsigned short ulo, uhi;
    __builtin_memcpy(&ulo, &lo, 2);
    __builtin_memcpy(&uhi, &hi, 2);
    out[j] = (unsigned int)ulo | ((unsigned int)uhi << 16);
}

// un-rematerializable prefetch load (compiler may NOT move/duplicate it)
#define GLOAD(dst, ptr, OFF) \
    asm volatile("global_load_dwordx4 %0, %1, off offset:" #OFF \
                 : "=&v"(dst) : "v"(ptr))

// issue next-step's 6 streamed W chunks (rows 1-3); consumed after vmcnt(0)
#define PREFETCH() do { \
    GLOAD(U2, pA, 0); GLOAD(U3, pA, 1024); GLOAD(U4, pA, 2048); \
    GLOAD(U5, pB, 0); GLOAD(U6, pB, 1024); GLOAD(U7, pB, 2048); \
} while (0)

// 4 x v_dot2_f32_f16: 8 MACs, f32 accumulate
#define DOT4(ACC, Tv, Hv) do { \
    ACC = __builtin_amdgcn_fdot2(bc2((Tv)[0]), bc2((Hv)[0]), ACC, false); \
    ACC = __builtin_amdgcn_fdot2(bc2((Tv)[1]), bc2((Hv)[1]), ACC, false); \
    ACC = __builtin_amdgcn_fdot2(bc2((Tv)[2]), bc2((Hv)[2]), ACC, false); \
    ACC = __builtin_amdgcn_fdot2(bc2((Tv)[3]), bc2((Hv)[3]), ACC, false); \
} while (0)

#define RED16(A) do { \
    A = dpp_add<0xB1>(A); A = dpp_add<0x4E>(A); \
    A = dpp_add<0x124>(A); A = dpp_add<0x128>(A); \
} while (0)

// Round 15: r14's pipe accounting closed exactly (LDS 1400 + serialized VMEM
// convoy = 1836 cyc/step). Fix: (a) rebalance -- only 1 W-row in LDS, 3 rows
// streamed; (b) 1-iteration-ahead prefetch via asm-volatile global_load
// (cannot be remat'd back to the consume point, unlike r13's plain loads),
// s_waitcnt vmcnt(0)+sched_barrier at consume (rule #18 / T14 pattern).
// Weights are step-invariant so the prefetched values are always correct.
__global__ __launch_bounds__(NTHR)
void rnn_persist(
    const float* __restrict__ x,      // [B, T, 1]
    const float* __restrict__ W_ih,   // [256, 1]
    const u32x4* __restrict__ wq,     // packed fp16 W_hh (d_ws)
    const float* __restrict__ b_ih,   // [256]
    const float* __restrict__ b_hh,   // [256]
    const float* __restrict__ W_out,  // [1, 256]
    const float* __restrict__ b_out,  // [1]
    float* __restrict__ y)            // [B, T, 1]
{
    // W row 0 of each thread's 4-row slice: resident in LDS (32 KB)
    __shared__ u32x4 s_w[2048];
    __shared__ float s_x[TT];
    // h as fp16, 16 chunks of 16 halfs, stride 24 ushorts (conflict-free, r14)
    __shared__ __align__(16) unsigned short s_hh[2][16 * 24];
    __shared__ float s_part[2][16];
    // occupancy clamp: total LDS > 80KB -> 1 block/CU -> RA budget 128 VGPR
    __shared__ float s_pad[10240];   // 40 KB

    const int tid  = threadIdx.x;
    const int c3   = tid & 15;
    const int rg   = tid >> 4;
    const int lane = tid & 63;
    const int wv   = tid >> 6;
    const int b    = blockIdx.x;

    // keep s_pad alive (volatile access on unprovable-false path)
    if (b == -1) {
        volatile float* vp = s_pad;
        vp[tid] = 1.0f;
        y[tid] = vp[tid];
    }

    for (int k = tid; k < TT; k += NTHR) s_x[k] = x[(size_t)b * TT + k];

    // copy W row 0 (chunks 0,1 per wave-slot): LDS j=(wv*2+i)*64+lane
    for (int j = tid; j < 2048; j += NTHR)
        s_w[j] = wq[((j >> 7) * 8 + ((j >> 6) & 1)) * 64 + (j & 63)];

    // zero h buffers
    if (tid < 768) (&s_hh[0][0])[tid] = 0;

    const int   myrow = 4 * rg + (c3 & 3);
    const float wih   = W_ih[myrow];
    const float bias  = b_ih[myrow] + b_hh[myrow];
    const float wo_my = W_out[myrow];
    const float bout  = b_out[0];

    const u32x4* lbase = s_w + (wv * 2) * 64 + lane;            // LDS W row 0
    const u32x4* pA = wq + (size_t)(wv * 8 + 2) * 64 + lane;    // chunks 2,3,4
    const u32x4* pB = wq + (size_t)(wv * 8 + 5) * 64 + lane;    // chunks 5,6,7
    const int hwidx  = 24 * (myrow >> 4) + (myrow & 15);
    const int hrbase = 24 * c3;

    u32x4 U2, U3, U4, U5, U6, U7;
    PREFETCH();               // prologue: loads for step 0 in flight

    __syncthreads();

    int p = 0;
    float* yrow = y + (size_t)b * TT;

    for (int step = 0; step <= TT; ++step) {
        // finalize y_{step-1}: rotating wave sums the 16 per-wave partials
        if (step >= 1 && wv == ((step - 1) & 15)) {
            float pp = s_part[(step - 1) & 1][lane & 15];
            pp = dpp_add<0xB1>(pp);
            pp = dpp_add<0x4E>(pp);
            pp = dpp_add<0x124>(pp);
            pp = dpp_add<0x128>(pp);
            if (lane == 0) yrow[step - 1] = pp + bout;
        }
        if (step == TT) break;

        // h (fp16): 2 x ds_read_b128
        const u32x4 H0 = *(const u32x4*)&s_hh[p][hrbase];
        const u32x4 H1 = *(const u32x4*)&s_hh[p][hrbase + 8];
        // LDS W row 0
        const u32x4 L0 = lbase[0];
        const u32x4 L1 = lbase[64];

        const float xt = s_x[step];

        float acc0 = 0.0f, acc1 = 0.0f, acc2 = 0.0f, acc3 = 0.0f;
        DOT4(acc0, L0, H0); DOT4(acc0, L1, H1);

        // streamed rows 1-3: prefetched LAST iteration -> latency already paid
        asm volatile("s_waitcnt vmcnt(0)" ::: "memory");
        __builtin_amdgcn_sched_barrier(0);
        DOT4(acc1, U2, H0); DOT4(acc1, U3, H1);
        DOT4(acc2, U4, H0); DOT4(acc2, U5, H1);
        DOT4(acc3, U6, H0); DOT4(acc3, U7, H1);

        PREFETCH();           // issue next step's loads; ~full step of slack

        RED16(acc0); RED16(acc1); RED16(acc2); RED16(acc3);

        float s01 = (c3 & 1) ? acc1 : acc0;
        float s23 = (c3 & 1) ? acc3 : acc2;
        float dot = (c3 & 2) ? s23 : s01;
        float hn  = tanh_fast(fmaf(xt, wih, bias) + dot);

        if ((c3 & 12) == 0) {   // c3 < 4: write h as fp16
            _Float16 hh = (_Float16)hn;
            unsigned short us;
            __builtin_memcpy(&us, &hh, 2);
            s_hh[p ^ 1][hwidx] = us;
        }

        float pv = ((c3 & 12) == 0) ? hn * wo_my : 0.0f;
        pv = dpp_add<0xB1>(pv);
        pv = dpp_add<0x4E>(pv);
        pv = dpp_add<0x124>(pv);
        pv = dpp_add<0x128>(pv);
        pv = dpp_add<0x142>(pv);   // row_bcast15
        pv = dpp_add<0x143>(pv);   // row_bcast31 -> lane63 holds full sum
        if (lane == 63) s_part[step & 1][wv] = pv;

        __syncthreads();
        p ^= 1;
    }
}

extern "C" void kernel_launch(void* const* d_in, const int* in_sizes, int n_in,
                              void* d_out, int out_size, void* d_ws, size_t ws_size,
                              hipStream_t stream) {
    const float* x     = (const float*)d_in[0];
    const float* W_ih  = (const float*)d_in[1];
    const float* W_hh  = (const float*)d_in[2];
    const float* b_ih  = (const float*)d_in[3];
    const float* b_hh  = (const float*)d_in[4];
    const float* W_out = (const float*)d_in[5];
    const float* b_out = (const float*)d_in[6];
    float* y = (float*)d_out;
    unsigned int* wpk = (unsigned int*)d_ws;   // 32768 u32 = 128 KB

    hipLaunchKernelGGL(pack_w, dim3(128), dim3(256), 0, stream, W_hh, wpk);
    hipLaunchKernelGGL(rnn_persist, dim3(NB), dim3(NTHR), 0, stream,
                       x, W_ih, (const u32x4*)wpk, b_ih, b_hh, W_out, b_out, y);
}